// Round 3
// baseline (11.939 us; speedup 1.0000x reference)
//
#include <hip/hip_runtime.h>

// The reference network is input-independent: conv1 has kernel width 1,
// stride 2, padding 1 on a width-1 input, so both output columns sample
// only zero-padding and conv1's output is leaky(b1) broadcast. Everything
// downstream is a closed-form function of the weights only.
//
// Launch-latency-bound problem. Single kernel, 45 expert-pairs x 8 row
// chunks = 360 two-wave blocks. Wave w of a block evaluates expert 2p+w
// (bit-identical arithmetic across chunks); the block then writes its
// 256-row slice of the two adjacent output columns as aligned float2.
// All global weight loads are issued at kernel entry (register prefetch)
// so the dependent-HBM-latency chain is ~1 round trip, not 4.

#define SLOPE 0.33f
#define NCHUNK 8
#define BATCH 2048

__device__ __forceinline__ float leaky(float v) {
    return v >= 0.0f ? v : SLOPE * v;
}

__global__ void __launch_bounds__(128) fused_pair_broadcast(
    const float* __restrict__ b1,   // [90,16]
    const float* __restrict__ W2,   // [90,32,16,3]
    const float* __restrict__ b2,   // [90,32]
    const float* __restrict__ W3,   // [90,64,32,3]
    const float* __restrict__ b3,   // [90,64]
    const float* __restrict__ Wfc,  // [90,64]
    const float* __restrict__ bfc,  // [90]
    float* __restrict__ out)        // [2048,90]
{
    const int p     = blockIdx.x / NCHUNK;   // expert pair index (0..44)
    const int chunk = blockIdx.x % NCHUNK;
    const int w = threadIdx.x >> 6;          // wave id: expert = 2p + w
    const int t = threadIdx.x & 63;
    const int e = 2 * p + w;

    __shared__ float t2s[2][32], m2s[2][32], u2s[2][32];
    __shared__ float vals[2];

    // ---- Prefetch: issue ALL global loads up front (hide HBM latency). ----
    const float* w3p = W3 + (size_t)(e * 64 + t) * 96;  // 384B aligned
    float w3r[96];
    #pragma unroll
    for (int i = 0; i < 24; ++i)
        *(float4*)&w3r[4 * i] = *(const float4*)&w3p[4 * i];
    const float b3v  = b3[e * 64 + t];
    const float wfcv = Wfc[e * 64 + t];
    const float bfcv = bfc[e];

    // ---- Stage 1+2 (lanes 0..31): conv1 out = leaky(b1[c]) everywhere;
    // conv2 w-col 1 has 3 distinct row values (top: taps 1,2; mid x21:
    // all taps; bottom: taps 0,1). ----
    if (t < 32) {
        const float* w2 = W2 + (size_t)(e * 32 + t) * 48;
        float stop = 0.f, smid = 0.f, sbot = 0.f;
        #pragma unroll
        for (int c = 0; c < 16; ++c) {
            float w0  = w2[c * 3 + 0];
            float w1  = w2[c * 3 + 1];
            float w2v = w2[c * 3 + 2];
            float a = leaky(b1[e * 16 + c]);   // broadcast load, bit-exact
            stop += a * (w1 + w2v);
            smid += a * (w0 + w1 + w2v);
            sbot += a * (w0 + w1);
        }
        float b = b2[e * 32 + t];
        t2s[w][t] = leaky(b + stop);   // h2 = 0
        m2s[w][t] = leaky(b + smid);   // h2 = 1..21 (21 rows)
        u2s[w][t] = leaky(b + sbot);   // h2 = 22
    }
    __syncthreads();

    // ---- Stage 3 + pool + fc (all 64 lanes; lane = output channel). ----
    //   w-col 0 of conv3 out = leaky(b3) (12 rows); w-col 1:
    //   h3=0: W3[.,c,1]*t2 + W3[.,c,2]*m2; h3=1..10: (taps sum)*m2;
    //   h3=11: W3[.,c,0]*m2 + W3[.,c,1]*u2
    float stop = 0.f, smid = 0.f, sbot = 0.f;
    #pragma unroll
    for (int c = 0; c < 32; ++c) {
        float w0  = w3r[c * 3 + 0];
        float w1  = w3r[c * 3 + 1];
        float w2v = w3r[c * 3 + 2];
        float m = m2s[w][c];
        stop += w1 * t2s[w][c] + w2v * m;
        smid += (w0 + w1 + w2v) * m;
        sbot += w0 * m + w1 * u2s[w][c];
    }
    float pooled = (12.0f * leaky(b3v)
                    + leaky(b3v + stop)
                    + 10.0f * leaky(b3v + smid)
                    + leaky(b3v + sbot)) * (1.0f / 24.0f);

    // fc: butterfly reduce so all lanes hold the dot product.
    float sum = wfcv * pooled;
    #pragma unroll
    for (int off = 32; off > 0; off >>= 1)
        sum += __shfl_xor(sum, off, 64);
    if (t == 0) vals[w] = leaky(sum + bfcv);
    __syncthreads();

    // ---- Write this chunk's 256 rows of columns (2p, 2p+1) as float2. ----
    const float2 v2 = make_float2(vals[0], vals[1]);
    const int rows_per_chunk = BATCH / NCHUNK;           // 256
    const int r0 = chunk * rows_per_chunk;
    #pragma unroll
    for (int i = 0; i < rows_per_chunk / 128; ++i) {     // 2 stores/thread
        int r = r0 + i * 128 + threadIdx.x;
        *(float2*)&out[(size_t)r * 90 + 2 * p] = v2;     // 360r+8p: 8B aligned
    }
}

extern "C" void kernel_launch(void* const* d_in, const int* in_sizes, int n_in,
                              void* d_out, int out_size, void* d_ws, size_t ws_size,
                              hipStream_t stream) {
    // setup_inputs order: x, W1, b1, W2, b2, W3, b3, Wfc, bfc
    // x (d_in[0]) and W1 (d_in[1]) are provably unused (conv1 sees only padding).
    const float* b1  = (const float*)d_in[2];
    const float* W2  = (const float*)d_in[3];
    const float* b2  = (const float*)d_in[4];
    const float* W3  = (const float*)d_in[5];
    const float* b3  = (const float*)d_in[6];
    const float* Wfc = (const float*)d_in[7];
    const float* bfc = (const float*)d_in[8];

    float* out = (float*)d_out;

    fused_pair_broadcast<<<45 * NCHUNK, 128, 0, stream>>>(
        b1, W2, b2, W3, b3, Wfc, bfc, out);
}

// Round 4
// 10.133 us; speedup vs baseline: 1.1782x; 1.1782x over previous
//
#include <hip/hip_runtime.h>

// The reference network is input-independent: conv1 has kernel width 1,
// stride 2, padding 1 on a width-1 input, so both output columns sample
// only zero-padding and conv1's output is leaky(b1) broadcast. Everything
// downstream is a closed-form function of the weights only.
//
// Launch-overhead-bound problem (~0.7 MFLOP, 737 KB writes). Single lean
// kernel: 90 experts x 8 row chunks = 720 one-wave blocks. Each block
// redundantly evaluates its expert's scalar (bit-identical across chunks)
// and writes its 256-row slice of that expert's output column.
// R3 post-mortem: register-array prefetch + cross-wave pairing regressed;
// this is the measured-best R2 structure minus one barrier/LDS stage.

#define SLOPE 0.33f
#define NCHUNK 8
#define BATCH 2048

__device__ __forceinline__ float leaky(float v) {
    return v >= 0.0f ? v : SLOPE * v;
}

__global__ void __launch_bounds__(64) fused_expert_broadcast(
    const float* __restrict__ b1,   // [90,16]
    const float* __restrict__ W2,   // [90,32,16,3]
    const float* __restrict__ b2,   // [90,32]
    const float* __restrict__ W3,   // [90,64,32,3]
    const float* __restrict__ b3,   // [90,64]
    const float* __restrict__ Wfc,  // [90,64]
    const float* __restrict__ bfc,  // [90]
    float* __restrict__ out)        // [2048,90]
{
    const int e     = blockIdx.x / NCHUNK;
    const int chunk = blockIdx.x % NCHUNK;
    const int t = threadIdx.x;

    __shared__ float t2s[32], m2s[32], u2s[32];

    // Stage 1+2 (lanes 0..31): conv1 out = leaky(b1[c]) everywhere (its
    // input patch is pure zero-padding); conv2 w-col 1 has 3 distinct row
    // values (top: taps 1,2; mid x21: all taps; bottom: taps 0,1).
    if (t < 32) {
        const float* w2 = W2 + (size_t)(e * 32 + t) * 48;
        float stop = 0.f, smid = 0.f, sbot = 0.f;
        #pragma unroll
        for (int c = 0; c < 16; ++c) {
            float w0  = w2[c * 3 + 0];
            float w1  = w2[c * 3 + 1];
            float w2v = w2[c * 3 + 2];
            float a = leaky(b1[e * 16 + c]);   // broadcast load, bit-exact
            stop += a * (w1 + w2v);
            smid += a * (w0 + w1 + w2v);
            sbot += a * (w0 + w1);
        }
        float b = b2[e * 32 + t];
        t2s[t] = leaky(b + stop);   // h2 = 0
        m2s[t] = leaky(b + smid);   // h2 = 1..21 (21 rows)
        u2s[t] = leaky(b + sbot);   // h2 = 22
    }
    __syncthreads();

    // Stage 3 + pool + fc (all 64 lanes; lane = conv3 output channel).
    //   w-col 0 of conv3 out = leaky(b3) (12 rows); w-col 1:
    //   h3=0: W3[.,c,1]*t2 + W3[.,c,2]*m2; h3=1..10: (taps sum)*m2;
    //   h3=11: W3[.,c,0]*m2 + W3[.,c,1]*u2
    const float* w3 = W3 + (size_t)(e * 64 + t) * 96;
    float stop = 0.f, smid = 0.f, sbot = 0.f;
    #pragma unroll
    for (int c = 0; c < 32; ++c) {
        float w0  = w3[c * 3 + 0];
        float w1  = w3[c * 3 + 1];
        float w2v = w3[c * 3 + 2];
        float m = m2s[c];
        stop += w1 * t2s[c] + w2v * m;
        smid += (w0 + w1 + w2v) * m;
        sbot += w0 * m + w1 * u2s[c];
    }
    float b = b3[e * 64 + t];
    float pooled = (12.0f * leaky(b)
                    + leaky(b + stop)
                    + 10.0f * leaky(b + smid)
                    + leaky(b + sbot)) * (1.0f / 24.0f);

    // fc: butterfly reduce so all lanes hold the dot product.
    float sum = Wfc[e * 64 + t] * pooled;
    #pragma unroll
    for (int off = 32; off > 0; off >>= 1)
        sum += __shfl_xor(sum, off, 64);
    const float val = leaky(sum + bfc[e]);

    // Write this chunk's 256 rows of column e (4 dword stores per lane).
    const int rows_per_chunk = BATCH / NCHUNK;  // 256
    const int r0 = chunk * rows_per_chunk;
    #pragma unroll
    for (int i = 0; i < rows_per_chunk / 64; ++i) {
        int r = r0 + i * 64 + t;
        out[(size_t)r * 90 + e] = val;
    }
}

extern "C" void kernel_launch(void* const* d_in, const int* in_sizes, int n_in,
                              void* d_out, int out_size, void* d_ws, size_t ws_size,
                              hipStream_t stream) {
    // setup_inputs order: x, W1, b1, W2, b2, W3, b3, Wfc, bfc
    // x (d_in[0]) and W1 (d_in[1]) are provably unused (conv1 sees only padding).
    const float* b1  = (const float*)d_in[2];
    const float* W2  = (const float*)d_in[3];
    const float* b2  = (const float*)d_in[4];
    const float* W3  = (const float*)d_in[5];
    const float* b3  = (const float*)d_in[6];
    const float* Wfc = (const float*)d_in[7];
    const float* bfc = (const float*)d_in[8];

    float* out = (float*)d_out;

    fused_expert_broadcast<<<90 * NCHUNK, 64, 0, stream>>>(
        b1, W2, b2, W3, b3, Wfc, bfc, out);
}